// Round 14
// baseline (99.980 us; speedup 1.0000x reference)
//
#include <hip/hip_runtime.h>

#define KS    7
#define RAD   3
#define TW    32            // tile width (output px)
#define TH    16            // tile height
#define HR    22            // halo rows
#define PAIRS 21            // col-pairs per parity row (19 needed, +2 pad)
#define NSITE (HR*2*PAIRS)  // 924 sites
#define H     256
#define W     256
#define HWp   (H*W)

typedef __fp16    h2raw __attribute__((ext_vector_type(2)));
typedef _Float16  f16x2 __attribute__((ext_vector_type(2)));

__device__ __forceinline__ unsigned pk(float a, float b) {
    h2raw h = __builtin_amdgcn_cvt_pkrtz(a, b);
    return __builtin_bit_cast(unsigned, h);
}
__device__ __forceinline__ f16x2 pkh(float a, float b) {
    return __builtin_bit_cast(f16x2, __builtin_amdgcn_cvt_pkrtz(a, b));
}
__device__ __forceinline__ f16x2 bch(unsigned u) {
    return __builtin_bit_cast(f16x2, u);
}

#if __has_builtin(__builtin_amdgcn_fdot2)
__device__ __forceinline__ float fdot2(f16x2 a, f16x2 b, float c) {
    return __builtin_amdgcn_fdot2(a, b, c, false);
}
#else
__device__ __forceinline__ float fdot2(f16x2 a, f16x2 b, float c) {
    return c + (float)a.x * (float)b.x + (float)a.y * (float)b.y;
}
#endif

__global__ __launch_bounds__(256, 2)
void bilateral_kernel(const float* __restrict__ in,      // [B][32][H][W]
                      const float* __restrict__ guide,   // [B][3][H][W]
                      const float* __restrict__ sigma_p, // [1]
                      float* __restrict__ out)           // [B][32][H][W]
{
    // parity-split site: (row,col) -> (row*2 + (col&1))*PAIRS + (col>>1)
    __shared__ uint2 gt2[NSITE];                          // {pk(x~,y~), pk(z~,q~)}
    __shared__ __align__(16) unsigned dtu[2][NSITE * 4];  // 2 grp x 8ch fp16/site

    const int tid = threadIdx.x;
    const int tx  = tid & 15;            // x-pair 0..15
    const int ty  = tid >> 4;            // row 0..15
    const int x0  = blockIdx.x * TW;
    const int y0  = blockIdx.y * TH;
    const int b   = blockIdx.z >> 1;
    const int cg0 = (blockIdx.z & 1) * 16;

    const float* gb  = guide + (size_t)b * 3 * HWp;
    const float* inb = in    + ((size_t)b * 32 + cg0) * HWp;

    const float sigma = sigma_p[0];
    const float isig2 = 1.0f / (sigma * sigma);
    const float L2E   = 1.442695041f;          // log2(e)
    const float SQL   = 1.201122409f;          // sqrt(log2(e))
    float lnT2[KS];
#pragma unroll
    for (int i = 0; i < KS; ++i) {
        float r = (float)(i - RAD);
        lnT2[i] = -0.5f * r * r * isig2 * L2E;
    }

    // ---- guide staging: 220 quad-tasks (one per thread), fp16-packed ----
    if (tid < HR * 10) {
        int row = tid / 10, q = tid - row * 10;
        int gy  = y0 - RAD + row;
        int gxb = x0 - 4 + 4 * q;                 // 4-aligned quad
        bool v = (gy >= 0) && (gy < H) && (gxb >= 0) && (gxb < W);
        float4 X = make_float4(0.f, 0.f, 0.f, 0.f);
        float4 Y = X, Z = X;
        if (v) {
            const float* p = gb + gy * W + gxb;
            X = *(const float4*)p;
            Y = *(const float4*)(p + HWp);
            Z = *(const float4*)(p + 2 * HWp);
        }
        int s0 = row * 2 * PAIRS + 2 * q;
        const float xs[4] = {X.x, X.y, X.z, X.w};
        const float ys[4] = {Y.x, Y.y, Y.z, Y.w};
        const float zs[4] = {Z.x, Z.y, Z.z, Z.w};
        const int   st[4] = {s0 + PAIRS - 1, s0, s0 + PAIRS, s0 + 1};
#pragma unroll
        for (int j = 0; j < 4; ++j) {
            if ((q == 0 && j == 0) || (q == 9 && j == 3)) continue;
            float ax = xs[j] * SQL, ay = ys[j] * SQL, az = zs[j] * SQL;
            float qv = -0.5f * (ax * ax + ay * ay + az * az);
            gt2[st[j]] = make_uint2(pk(ax, ay), pk(az, qv));
        }
    }

    // ---- input staging: 1760 tasks (row, q, cpair 0..7) ----
    for (int t = tid; t < HR * 10 * 8; t += 256) {
        int row = t / 80;
        int rem = t - row * 80;
        int q   = rem >> 3;
        int cp  = rem & 7;
        int gy  = y0 - RAD + row;
        int gxb = x0 - 4 + 4 * q;
        bool v = (gy >= 0) && (gy < H) && (gxb >= 0) && (gxb < W);
        float4 A = make_float4(0.f, 0.f, 0.f, 0.f), B = A;
        if (v) {
            const float* p = inb + (size_t)(2 * cp) * HWp + gy * W + gxb;
            A = *(const float4*)p;
            B = *(const float4*)(p + HWp);
        }
        int s0 = row * 2 * PAIRS + 2 * q;
        unsigned* dst = &dtu[cp >> 2][cp & 3];
        if (q != 0) dst[(s0 + PAIRS - 1) * 4] = pk(A.x, B.x);
        dst[s0 * 4]           = pk(A.y, B.y);
        dst[(s0 + PAIRS) * 4] = pk(A.z, B.z);
        if (q != 9) dst[(s0 + 1) * 4]     = pk(A.w, B.w);
    }
    __syncthreads();

    // ---- centers: px0 col 2tx+3 (par1, pair tx+1); px1 col 2tx+4 (par0, pair tx+2)
    const int cb = (ty + RAD) * 2 * PAIRS;
    uint2 c0r = gt2[cb + PAIRS + tx + 1];
    uint2 c1r = gt2[cb + tx + 2];
    const f16x2 c0xy = bch(c0r.x), c1xy = bch(c1r.x);
    f16x2 c0zq = bch(c0r.y), c1zq = bch(c1r.y);
    const float qc0 = (float)c0zq.y, qc1 = (float)c1zq.y;
    f16x2 c0z1, c1z1;
    c0z1.x = c0zq.x; c0z1.y = (_Float16)1.0f;
    c1z1.x = c1zq.x; c1z1.y = (_Float16)1.0f;

    float nsum0 = 0.f, nsum1 = 0.f;
    float acc0[16], acc1[16];
#pragma unroll
    for (int c = 0; c < 16; ++c) { acc0[c] = 0.f; acc1[c] = 0.f; }
    f16x2 A0[2][4], A1[2][4];
#pragma unroll
    for (int g = 0; g < 2; ++g)
#pragma unroll
        for (int w = 0; w < 4; ++w) { A0[g][w] = (f16x2)0; A1[g][w] = (f16x2)0; }

    // ---- fused rows: weights (row-local, no wk array) + 2-group apply ----
#pragma unroll
    for (int i = 0; i < KS; ++i) {
        const int rb = (ty + i) * 2 * PAIRS;
        // guide row: 8 sites (b64, conflict-free contiguous per parity)
        uint2 gq[8];
#pragma unroll
        for (int k = 0; k < 8; ++k)
            gq[k] = gt2[rb + (k & 1) * PAIRS + tx + (k >> 1)];
        const float Qi0 = lnT2[i] + qc0;
        const float Qi1 = lnT2[i] + qc1;
        f16x2 wh0[KS], wh1[KS];
#pragma unroll
        for (int k = 0; k < KS; ++k) {
            float e0 = fdot2(bch(gq[k].x), c0xy,
                             fdot2(bch(gq[k].y), c0z1, Qi0 + lnT2[k]));
            float w0 = exp2f(e0);
            nsum0 += w0;
            wh0[k] = pkh(w0, w0);
            float e1 = fdot2(bch(gq[k + 1].x), c1xy,
                             fdot2(bch(gq[k + 1].y), c1z1, Qi1 + lnT2[k]));
            float w1 = exp2f(e1);
            nsum1 += w1;
            wh1[k] = pkh(w1, w1);
        }
        // apply both channel groups with these row weights
#pragma unroll
        for (int g = 0; g < 2; ++g) {
            const uint4* dg = (const uint4*)&dtu[g][0];
            uint4 rq[8];
#pragma unroll
            for (int k = 0; k < 8; ++k)
                rq[k] = dg[rb + (k & 1) * PAIRS + tx + (k >> 1)];
#pragma unroll
            for (int k = 0; k < KS; ++k) {
                A0[g][0] = wh0[k] * bch(rq[k].x) + A0[g][0];
                A0[g][1] = wh0[k] * bch(rq[k].y) + A0[g][1];
                A0[g][2] = wh0[k] * bch(rq[k].z) + A0[g][2];
                A0[g][3] = wh0[k] * bch(rq[k].w) + A0[g][3];
                A1[g][0] = wh1[k] * bch(rq[k + 1].x) + A1[g][0];
                A1[g][1] = wh1[k] * bch(rq[k + 1].y) + A1[g][1];
                A1[g][2] = wh1[k] * bch(rq[k + 1].z) + A1[g][2];
                A1[g][3] = wh1[k] * bch(rq[k + 1].w) + A1[g][3];
            }
        }
        if (i == 3 || i == KS - 1) {   // bound fp16 chains at <=28 taps
#pragma unroll
            for (int g = 0; g < 2; ++g)
#pragma unroll
                for (int w = 0; w < 4; ++w) {
                    acc0[g * 8 + 2 * w]     += (float)A0[g][w].x;
                    acc0[g * 8 + 2 * w + 1] += (float)A0[g][w].y;
                    acc1[g * 8 + 2 * w]     += (float)A1[g][w].x;
                    acc1[g * 8 + 2 * w + 1] += (float)A1[g][w].y;
                    A0[g][w] = (f16x2)0;
                    A1[g][w] = (f16x2)0;
                }
        }
    }

    // ---- normalize + store (norm >= center weight ~= 1, never 0) ----
    const float i0 = 1.f / nsum0, i1 = 1.f / nsum1;
    const int X = x0 + 2 * tx, Yo = y0 + ty;
    float* ob = out + ((size_t)b * 32 + cg0) * HWp + (size_t)Yo * W + X;
#pragma unroll
    for (int c = 0; c < 16; ++c) {
        float2 s;
        s.x = acc0[c] * i0;
        s.y = acc1[c] * i1;
        *(float2*)(ob + (size_t)c * HWp) = s;
    }
}

extern "C" void kernel_launch(void* const* d_in, const int* in_sizes, int n_in,
                              void* d_out, int out_size, void* d_ws, size_t ws_size,
                              hipStream_t stream) {
    const float* in    = (const float*)d_in[0];
    const float* guide = (const float*)d_in[1];
    const float* sigma = (const float*)d_in[2];
    float* out = (float*)d_out;
    dim3 grid(W / TW, H / TH, 2 * 2);   // z = batch*2 + 16ch-half
    bilateral_kernel<<<grid, dim3(256), 0, stream>>>(in, guide, sigma, out);
}

// Round 15
// 29.862 us; speedup vs baseline: 3.3481x; 3.3481x over previous
//
#include <hip/hip_runtime.h>

#define KS    7
#define RAD   3
#define TW    32            // tile width (output px)
#define TH    16            // tile height
#define HR    22            // halo rows
#define PAIRS 21            // col-pairs per parity row (19 needed, +2 pad)
#define NSITE (HR*2*PAIRS)  // 924 sites
#define H     256
#define W     256
#define HWp   (H*W)

typedef __fp16    h2raw __attribute__((ext_vector_type(2)));
typedef _Float16  f16x2 __attribute__((ext_vector_type(2)));

__device__ __forceinline__ unsigned pk(float a, float b) {
    h2raw h = __builtin_amdgcn_cvt_pkrtz(a, b);
    return __builtin_bit_cast(unsigned, h);
}
__device__ __forceinline__ f16x2 bch(unsigned u) {
    return __builtin_bit_cast(f16x2, u);
}

#if __has_builtin(__builtin_amdgcn_fdot2)
__device__ __forceinline__ float fdot2(f16x2 a, f16x2 b, float c) {
    return __builtin_amdgcn_fdot2(a, b, c, false);
}
#else
__device__ __forceinline__ float fdot2(f16x2 a, f16x2 b, float c) {
    return c + (float)a.x * (float)b.x + (float)a.y * (float)b.y;
}
#endif

__global__ __launch_bounds__(512, 4)
void bilateral_kernel(const float* __restrict__ in,      // [B][32][H][W]
                      const float* __restrict__ guide,   // [B][3][H][W]
                      const float* __restrict__ sigma_p, // [1]
                      float* __restrict__ out)           // [B][32][H][W]
{
    // parity-split site: (row,col) -> (row*2 + (col&1))*PAIRS + (col>>1)
    __shared__ uint2 gt2[NSITE];                          // {pk(x~,y~), pk(z~,q~)}
    __shared__ __align__(16) unsigned dtu[2][NSITE * 4];  // 2 grp x 8ch fp16/site

    const int tid = threadIdx.x;
    const int tx  = tid & 31;            // output col 0..31
    const int ty  = tid >> 5;            // output row 0..15
    const int x0  = blockIdx.x * TW;
    const int y0  = blockIdx.y * TH;
    const int b   = blockIdx.z >> 1;
    const int cg0 = (blockIdx.z & 1) * 16;

    const float* gb  = guide + (size_t)b * 3 * HWp;
    const float* inb = in    + ((size_t)b * 32 + cg0) * HWp;

    const float sigma = sigma_p[0];
    const float isig2 = 1.0f / (sigma * sigma);
    const float L2E   = 1.442695041f;          // log2(e)
    const float SQL   = 1.201122409f;          // sqrt(log2(e))
    float lnT2[KS];
#pragma unroll
    for (int i = 0; i < KS; ++i) {
        float r = (float)(i - RAD);
        lnT2[i] = -0.5f * r * r * isig2 * L2E;
    }

    // ---- guide staging: 220 quad-tasks (one per thread), fp16-packed ----
    if (tid < HR * 10) {
        int row = tid / 10, q = tid - row * 10;
        int gy  = y0 - RAD + row;
        int gxb = x0 - 4 + 4 * q;                 // 4-aligned quad
        bool v = (gy >= 0) && (gy < H) && (gxb >= 0) && (gxb < W);
        float4 X = make_float4(0.f, 0.f, 0.f, 0.f);
        float4 Y = X, Z = X;
        if (v) {
            const float* p = gb + gy * W + gxb;
            X = *(const float4*)p;
            Y = *(const float4*)(p + HWp);
            Z = *(const float4*)(p + 2 * HWp);
        }
        int s0 = row * 2 * PAIRS + 2 * q;         // site of col 4q (parity0)
        const float xs[4] = {X.x, X.y, X.z, X.w};
        const float ys[4] = {Y.x, Y.y, Y.z, Y.w};
        const float zs[4] = {Z.x, Z.y, Z.z, Z.w};
        const int   st[4] = {s0 + PAIRS - 1, s0, s0 + PAIRS, s0 + 1};
#pragma unroll
        for (int j = 0; j < 4; ++j) {
            if ((q == 0 && j == 0) || (q == 9 && j == 3)) continue;  // col -1/38
            float ax = xs[j] * SQL, ay = ys[j] * SQL, az = zs[j] * SQL;
            float qv = -0.5f * (ax * ax + ay * ay + az * az);
            gt2[st[j]] = make_uint2(pk(ax, ay), pk(az, qv));
        }
    }

    // ---- input staging: 1760 tasks (row, q, cpair 0..7), float4 quads ----
    for (int t = tid; t < HR * 10 * 8; t += 512) {
        int row = t / 80;
        int rem = t - row * 80;
        int q   = rem >> 3;
        int cp  = rem & 7;                        // channel pair within 16
        int gy  = y0 - RAD + row;
        int gxb = x0 - 4 + 4 * q;
        bool v = (gy >= 0) && (gy < H) && (gxb >= 0) && (gxb < W);
        float4 A = make_float4(0.f, 0.f, 0.f, 0.f), B = A;
        if (v) {
            const float* p = inb + (size_t)(2 * cp) * HWp + gy * W + gxb;
            A = *(const float4*)p;
            B = *(const float4*)(p + HWp);
        }
        int s0 = row * 2 * PAIRS + 2 * q;
        unsigned* dst = &dtu[cp >> 2][cp & 3];
        if (q != 0) dst[(s0 + PAIRS - 1) * 4] = pk(A.x, B.x);
        dst[s0 * 4]           = pk(A.y, B.y);
        dst[(s0 + PAIRS) * 4] = pk(A.z, B.z);
        if (q != 9) dst[(s0 + 1) * 4]     = pk(A.w, B.w);
    }
    __syncthreads();

    // ---- per-column site offsets (hoisted) ----
    int colAdd[KS];
#pragma unroll
    for (int k = 0; k < KS; ++k) {
        int col = tx + k;
        colAdd[k] = (col & 1) * PAIRS + (col >> 1);
    }

    // ---- weights: 49 per thread (1 px), fp16 dot2 path, packed broadcast ----
    const int ccol = tx + RAD;
    uint2 cr = gt2[(ty + RAD) * 2 * PAIRS + (ccol & 1) * PAIRS + (ccol >> 1)];
    const f16x2 cxy = bch(cr.x);
    f16x2 czq = bch(cr.y);
    const float qc = (float)czq.y;
    f16x2 cz1;
    cz1.x = czq.x; cz1.y = (_Float16)1.0f;

    unsigned wkp[KS * KS];    // packed fp16 broadcast pairs
    float nsum = 0.f;
#pragma unroll
    for (int i = 0; i < KS; ++i) {
        const int rb = (ty + i) * 2 * PAIRS;
        const float Qi = lnT2[i] + qc;
#pragma unroll
        for (int k = 0; k < KS; ++k) {
            uint2 g = gt2[rb + colAdd[k]];
            float e = fdot2(bch(g.x), cxy, fdot2(bch(g.y), cz1, Qi + lnT2[k]));
            float w = exp2f(e);
            nsum += w;
            wkp[i * KS + k] = pk(w, w);
        }
    }
    const float inv = 1.f / nsum;   // >= center weight ~= 1, never 0

    // ---- apply: 2 channel-group phases, fp16 row-accumulate, f32 flush ----
    const int X = x0 + tx, Yo = y0 + ty;
#pragma unroll
    for (int g = 0; g < 2; ++g) {
        const uint4* dg = (const uint4*)&dtu[g][0];
        float acc[8];
#pragma unroll
        for (int c = 0; c < 8; ++c) acc[c] = 0.f;
#pragma unroll
        for (int i = 0; i < KS; ++i) {
            const int rb = (ty + i) * 2 * PAIRS;
            uint4 rq[KS];
#pragma unroll
            for (int k = 0; k < KS; ++k) rq[k] = dg[rb + colAdd[k]];
            f16x2 A0 = (f16x2)0, A1 = (f16x2)0, A2 = (f16x2)0, A3 = (f16x2)0;
#pragma unroll
            for (int k = 0; k < KS; ++k) {
                f16x2 wh = bch(wkp[i * KS + k]);
                A0 = wh * bch(rq[k].x) + A0;
                A1 = wh * bch(rq[k].y) + A1;
                A2 = wh * bch(rq[k].z) + A2;
                A3 = wh * bch(rq[k].w) + A3;
            }
            acc[0] += (float)A0.x; acc[1] += (float)A0.y;
            acc[2] += (float)A1.x; acc[3] += (float)A1.y;
            acc[4] += (float)A2.x; acc[5] += (float)A2.y;
            acc[6] += (float)A3.x; acc[7] += (float)A3.y;
        }
        float* ob = out + ((size_t)b * 32 + cg0 + 8 * g) * HWp + (size_t)Yo * W + X;
#pragma unroll
        for (int c = 0; c < 8; ++c)
            ob[(size_t)c * HWp] = acc[c] * inv;
    }
}

extern "C" void kernel_launch(void* const* d_in, const int* in_sizes, int n_in,
                              void* d_out, int out_size, void* d_ws, size_t ws_size,
                              hipStream_t stream) {
    const float* in    = (const float*)d_in[0];
    const float* guide = (const float*)d_in[1];
    const float* sigma = (const float*)d_in[2];
    float* out = (float*)d_out;
    dim3 grid(W / TW, H / TH, 2 * 2);   // z = batch*2 + 16ch-half
    bilateral_kernel<<<grid, dim3(512), 0, stream>>>(in, guide, sigma, out);
}

// Round 16
// 23.870 us; speedup vs baseline: 4.1885x; 1.2510x over previous
//
#include <hip/hip_runtime.h>

#define KS    7
#define RAD   3
#define TW    32            // tile width (output px)
#define TH    16            // tile height
#define HR    22            // halo rows
#define PAIRS 21            // col-pairs per parity row (19 needed, +2 pad)
#define NSITE (HR*2*PAIRS)  // 924 sites
#define H     256
#define W     256
#define HWp   (H*W)
#define NTASK (HR*10*4)     // 880 input staging tasks per group

typedef __fp16    h2raw __attribute__((ext_vector_type(2)));
typedef _Float16  f16x2 __attribute__((ext_vector_type(2)));

__device__ __forceinline__ unsigned pk(float a, float b) {
    h2raw h = __builtin_amdgcn_cvt_pkrtz(a, b);
    return __builtin_bit_cast(unsigned, h);
}
__device__ __forceinline__ f16x2 bch(unsigned u) {
    return __builtin_bit_cast(f16x2, u);
}

#if __has_builtin(__builtin_amdgcn_fdot2)
__device__ __forceinline__ float fdot2(f16x2 a, f16x2 b, float c) {
    return __builtin_amdgcn_fdot2(a, b, c, false);
}
#else
__device__ __forceinline__ float fdot2(f16x2 a, f16x2 b, float c) {
    return c + (float)a.x * (float)b.x + (float)a.y * (float)b.y;
}
#endif

// ---- issue group g's global loads into registers (no LDS touch) ----
#define ISSUE_IN(g) do {                                                    \
    _Pragma("unroll")                                                       \
    for (int j = 0; j < 2; ++j) {                                           \
        int t = tid + j * 512;                                              \
        iA[j] = make_float4(0.f, 0.f, 0.f, 0.f); iB[j] = iA[j];             \
        if (t < NTASK) {                                                    \
            int row = t / 40;                                               \
            int rem = t - row * 40;                                         \
            int q   = rem >> 2;                                             \
            int cp  = rem & 3;                                              \
            int gy  = y0 - RAD + row;                                       \
            int gxb = x0 - 4 + 4 * q;                                       \
            if (gy >= 0 && gy < H && gxb >= 0 && gxb < W) {                 \
                const float* p = inb + (size_t)((g) * 8 + 2 * cp) * HWp     \
                                 + gy * W + gxb;                            \
                iA[j] = *(const float4*)p;                                  \
                iB[j] = *(const float4*)(p + HWp);                          \
            }                                                               \
        }                                                                   \
    }                                                                       \
} while (0)

// ---- pack staged registers and write them to dtu[g] ----
#define WRITE_IN(g) do {                                                    \
    _Pragma("unroll")                                                       \
    for (int j = 0; j < 2; ++j) {                                           \
        int t = tid + j * 512;                                              \
        if (t < NTASK) {                                                    \
            int row = t / 40;                                               \
            int rem = t - row * 40;                                         \
            int q   = rem >> 2;                                             \
            int cp  = rem & 3;                                              \
            int s0  = row * 2 * PAIRS + 2 * q;                              \
            unsigned* dst = &dtu[(g)][cp];                                  \
            if (q != 0) dst[(s0 + PAIRS - 1) * 4] = pk(iA[j].x, iB[j].x);   \
            dst[s0 * 4]           = pk(iA[j].y, iB[j].y);                   \
            dst[(s0 + PAIRS) * 4] = pk(iA[j].z, iB[j].z);                   \
            if (q != 9) dst[(s0 + 1) * 4] = pk(iA[j].w, iB[j].w);           \
        }                                                                   \
    }                                                                       \
} while (0)

// ---- apply group g with the register-resident packed weights ----
#define APPLY(g) do {                                                       \
    const uint4* dg = (const uint4*)&dtu[(g)][0];                           \
    float acc[8];                                                           \
    _Pragma("unroll") for (int c = 0; c < 8; ++c) acc[c] = 0.f;             \
    _Pragma("unroll")                                                       \
    for (int i = 0; i < KS; ++i) {                                          \
        const int rb = (ty + i) * 2 * PAIRS;                                \
        uint4 rq[KS];                                                       \
        _Pragma("unroll")                                                   \
        for (int k = 0; k < KS; ++k) rq[k] = dg[rb + colAdd[k]];            \
        f16x2 A0 = (f16x2)0, A1 = (f16x2)0, A2 = (f16x2)0, A3 = (f16x2)0;   \
        _Pragma("unroll")                                                   \
        for (int k = 0; k < KS; ++k) {                                      \
            f16x2 wh = bch(wkp[i * KS + k]);                                \
            A0 = wh * bch(rq[k].x) + A0;                                    \
            A1 = wh * bch(rq[k].y) + A1;                                    \
            A2 = wh * bch(rq[k].z) + A2;                                    \
            A3 = wh * bch(rq[k].w) + A3;                                    \
        }                                                                   \
        acc[0] += (float)A0.x; acc[1] += (float)A0.y;                       \
        acc[2] += (float)A1.x; acc[3] += (float)A1.y;                       \
        acc[4] += (float)A2.x; acc[5] += (float)A2.y;                       \
        acc[6] += (float)A3.x; acc[7] += (float)A3.y;                       \
    }                                                                       \
    float* ob = out + ((size_t)b * 32 + (g) * 8) * HWp                      \
                + (size_t)Yo * W + Xo;                                      \
    _Pragma("unroll")                                                       \
    for (int c = 0; c < 8; ++c) ob[(size_t)c * HWp] = acc[c] * inv;         \
} while (0)

__global__ __launch_bounds__(512)
void bilateral_kernel(const float* __restrict__ in,      // [B][32][H][W]
                      const float* __restrict__ guide,   // [B][3][H][W]
                      const float* __restrict__ sigma_p, // [1]
                      float* __restrict__ out)           // [B][32][H][W]
{
    // parity-split site: (row,col) -> (row*2 + (col&1))*PAIRS + (col>>1)
    __shared__ uint2 gt2[NSITE];                          // {pk(x~,y~), pk(z~,q~)}
    __shared__ __align__(16) unsigned dtu[4][NSITE * 4];  // 4 grp x 8ch fp16/site

    const int tid = threadIdx.x;
    const int tx  = tid & 31;            // output col 0..31
    const int ty  = tid >> 5;            // output row 0..15
    const int x0  = blockIdx.x * TW;
    const int y0  = blockIdx.y * TH;
    const int b   = blockIdx.z;

    const float* gb  = guide + (size_t)b * 3  * HWp;
    const float* inb = in    + (size_t)b * 32 * HWp;

    const float sigma = sigma_p[0];
    const float isig2 = 1.0f / (sigma * sigma);
    const float L2E   = 1.442695041f;          // log2(e)
    const float SQL   = 1.201122409f;          // sqrt(log2(e))
    float lnT2[KS];
#pragma unroll
    for (int i = 0; i < KS; ++i) {
        float r = (float)(i - RAD);
        lnT2[i] = -0.5f * r * r * isig2 * L2E;
    }

    // ---- phase 0: issue guide loads, then group-0 input loads ----
    float4 gX = make_float4(0.f, 0.f, 0.f, 0.f), gY = gX, gZ = gX;
    int grow = 0, gq = 0;
    if (tid < HR * 10) {
        grow = tid / 10; gq = tid - grow * 10;
        int gy  = y0 - RAD + grow;
        int gxb = x0 - 4 + 4 * gq;                // 4-aligned quad
        if (gy >= 0 && gy < H && gxb >= 0 && gxb < W) {
            const float* p = gb + gy * W + gxb;
            gX = *(const float4*)p;
            gY = *(const float4*)(p + HWp);
            gZ = *(const float4*)(p + 2 * HWp);
        }
    }
    float4 iA[2], iB[2];
    ISSUE_IN(0);                                  // g0 loads fly from here on

    // ---- guide pack + LDS write ----
    if (tid < HR * 10) {
        int s0 = grow * 2 * PAIRS + 2 * gq;
        const float xs[4] = {gX.x, gX.y, gX.z, gX.w};
        const float ys[4] = {gY.x, gY.y, gY.z, gY.w};
        const float zs[4] = {gZ.x, gZ.y, gZ.z, gZ.w};
        const int   st[4] = {s0 + PAIRS - 1, s0, s0 + PAIRS, s0 + 1};
#pragma unroll
        for (int j = 0; j < 4; ++j) {
            if ((gq == 0 && j == 0) || (gq == 9 && j == 3)) continue;
            float ax = xs[j] * SQL, ay = ys[j] * SQL, az = zs[j] * SQL;
            float qv = -0.5f * (ax * ax + ay * ay + az * az);
            gt2[st[j]] = make_uint2(pk(ax, ay), pk(az, qv));
        }
    }
    __syncthreads();                              // gt2 ready

    // ---- per-column site offsets (hoisted) ----
    int colAdd[KS];
#pragma unroll
    for (int k = 0; k < KS; ++k) {
        int col = tx + k;
        colAdd[k] = (col & 1) * PAIRS + (col >> 1);
    }

    // ---- weights (g0 loads in flight underneath) ----
    const int ccol = tx + RAD;
    uint2 cr = gt2[(ty + RAD) * 2 * PAIRS + (ccol & 1) * PAIRS + (ccol >> 1)];
    const f16x2 cxy = bch(cr.x);
    f16x2 czq = bch(cr.y);
    const float qc = (float)czq.y;
    f16x2 cz1;
    cz1.x = czq.x; cz1.y = (_Float16)1.0f;

    unsigned wkp[KS * KS];
    float nsum = 0.f;
#pragma unroll
    for (int i = 0; i < KS; ++i) {
        const int rb = (ty + i) * 2 * PAIRS;
        const float Qi = lnT2[i] + qc;
#pragma unroll
        for (int k = 0; k < KS; ++k) {
            uint2 g = gt2[rb + colAdd[k]];
            float e = fdot2(bch(g.x), cxy, fdot2(bch(g.y), cz1, Qi + lnT2[k]));
            float w = exp2f(e);
            nsum += w;
            wkp[i * KS + k] = pk(w, w);
        }
    }
    const float inv = 1.f / nsum;   // >= center weight ~= 1, never 0
    const int Xo = x0 + tx, Yo = y0 + ty;

    // ---- pipelined: write g / issue g+1 / barrier / apply g ----
    WRITE_IN(0); ISSUE_IN(1);
    __syncthreads();              // dtu[0] ready
    APPLY(0);
    WRITE_IN(1); ISSUE_IN(2);
    __syncthreads();              // dtu[1] ready
    APPLY(1);
    WRITE_IN(2); ISSUE_IN(3);
    __syncthreads();              // dtu[2] ready
    APPLY(2);
    WRITE_IN(3);
    __syncthreads();              // dtu[3] ready
    APPLY(3);
}

extern "C" void kernel_launch(void* const* d_in, const int* in_sizes, int n_in,
                              void* d_out, int out_size, void* d_ws, size_t ws_size,
                              hipStream_t stream) {
    const float* in    = (const float*)d_in[0];
    const float* guide = (const float*)d_in[1];
    const float* sigma = (const float*)d_in[2];
    float* out = (float*)d_out;
    dim3 grid(W / TW, H / TH, 2);
    bilateral_kernel<<<grid, dim3(512), 0, stream>>>(in, guide, sigma, out);
}